// Round 4
// baseline (469.742 us; speedup 1.0000x reference)
//
#include <hip/hip_runtime.h>
#include <math.h>

#define BB 8
#define NN 512
#define CC 768
#define HH 12
#define HD 64
#define TOPK 90
#define QKV_ELEMS (BB*HH*NN*HD)   // 3145728 elements per q/k/v tensor
#define KC 2304                   // split-K: 3*768

typedef __attribute__((ext_vector_type(8))) short short8;   // 8 bf16 = 4 VGPR
typedef __attribute__((ext_vector_type(4))) float floatx4;  // MFMA C/D

__device__ inline unsigned short f2bf(float f) {
    unsigned int u = __float_as_uint(f);
    u += 0x7FFFu + ((u >> 16) & 1u);           // RNE
    return (unsigned short)(u >> 16);
}
__device__ inline float bf2f(unsigned short h) {
    return __uint_as_float(((unsigned int)h) << 16);
}

// ---------------------------------------------------------------------------
// Split kernels: fp32 [rows][768] -> bf16 [rows][2304].
// IS_A: blocks [hi | hi | lo]; !IS_A: blocks [hi | lo | hi]  (hh+hl+lh).
// ---------------------------------------------------------------------------
template<bool IS_A>
__global__ __launch_bounds__(256) void split_k(const float* __restrict__ in,
                                               unsigned short* __restrict__ o2,
                                               int total) {
    int idx = blockIdx.x * 256 + threadIdx.x;
    if (idx >= total) return;
    int e = idx * 4;
    int m = e / CC, kk = e - m * CC;
    float4 f = *(const float4*)(in + e);
    ushort4 hi, lo;
    hi.x = f2bf(f.x); lo.x = f2bf(f.x - bf2f(hi.x));
    hi.y = f2bf(f.y); lo.y = f2bf(f.y - bf2f(hi.y));
    hi.z = f2bf(f.z); lo.z = f2bf(f.z - bf2f(hi.z));
    hi.w = f2bf(f.w); lo.w = f2bf(f.w - bf2f(hi.w));
    unsigned short* base = o2 + (size_t)m * KC + kk;
    *(ushort4*)(base)        = hi;
    *(ushort4*)(base + CC)   = IS_A ? hi : lo;
    *(ushort4*)(base + 2*CC) = IS_A ? lo : hi;
}

// ---------------------------------------------------------------------------
// Split-bf16 MFMA GEMM (m97-style). QKV_EPI: q,k written as split bf16
// (qh/ql, kh/kl in [B,H,N,hd]), v written fp32. Else: out[m][NCOLS] + bias.
// ---------------------------------------------------------------------------
template<int NCOLS, bool QKV_EPI>
__global__ __launch_bounds__(256) void gemm_split(const unsigned short* __restrict__ A,
                                                  const unsigned short* __restrict__ Bm,
                                                  const float* __restrict__ bias,
                                                  float* __restrict__ out,
                                                  unsigned short* __restrict__ qh,
                                                  unsigned short* __restrict__ ql,
                                                  unsigned short* __restrict__ kh,
                                                  unsigned short* __restrict__ kl,
                                                  float* __restrict__ vout) {
    __shared__ char lds[16384];
    const int bm = blockIdx.x, bn = blockIdx.y;
    const int tid  = threadIdx.x;
    const int wave = tid >> 6, lane = tid & 63;
    const int wm = wave >> 1, wn = wave & 1;
    const int quad = lane >> 4, r = lane & 15;

    const int cA0 = tid, cA1 = tid + 256;
    const int mA0 = cA0 >> 2, oA0 = (cA0 & 3) ^ ((mA0 >> 1) & 3);
    const int mA1 = cA1 >> 2, oA1 = (cA1 & 3) ^ ((mA1 >> 1) & 3);
    const unsigned short* gA0 = A  + (size_t)(bm*128 + mA0) * KC + oA0*8;
    const unsigned short* gA1 = A  + (size_t)(bm*128 + mA1) * KC + oA1*8;
    const unsigned short* gB0 = Bm + (size_t)(bn*128 + mA0) * KC + oA0*8;
    const unsigned short* gB1 = Bm + (size_t)(bn*128 + mA1) * KC + oA1*8;
    char* lA0 = lds + (wave*64)*16;
    char* lA1 = lds + (256 + wave*64)*16;
    char* lB0 = lds + 8192 + (wave*64)*16;
    char* lB1 = lds + 8192 + (256 + wave*64)*16;

    const int octsel = quad ^ ((r >> 1) & 3);
    int aoff[4], boff[4];
#pragma unroll
    for (int i = 0; i < 4; ++i) {
        aoff[i] = ((wm*64 + i*16 + r)*4 + octsel) * 16;
        boff[i] = 8192 + ((wn*64 + i*16 + r)*4 + octsel) * 16;
    }

    floatx4 acc[4][4];
#pragma unroll
    for (int i = 0; i < 4; ++i)
#pragma unroll
        for (int j = 0; j < 4; ++j)
            acc[i][j] = (floatx4){0.f, 0.f, 0.f, 0.f};

    for (int it = 0; it < KC/32; ++it) {
        __syncthreads();
        __builtin_amdgcn_global_load_lds((const __attribute__((address_space(1))) unsigned int*)gA0,
                                         (__attribute__((address_space(3))) unsigned int*)lA0, 16, 0, 0);
        __builtin_amdgcn_global_load_lds((const __attribute__((address_space(1))) unsigned int*)gA1,
                                         (__attribute__((address_space(3))) unsigned int*)lA1, 16, 0, 0);
        __builtin_amdgcn_global_load_lds((const __attribute__((address_space(1))) unsigned int*)gB0,
                                         (__attribute__((address_space(3))) unsigned int*)lB0, 16, 0, 0);
        __builtin_amdgcn_global_load_lds((const __attribute__((address_space(1))) unsigned int*)gB1,
                                         (__attribute__((address_space(3))) unsigned int*)lB1, 16, 0, 0);
        gA0 += 32; gA1 += 32; gB0 += 32; gB1 += 32;
        asm volatile("s_waitcnt vmcnt(0)" ::: "memory");
        __syncthreads();

        short8 af[4], bf[4];
#pragma unroll
        for (int i = 0; i < 4; ++i) af[i] = *(const short8*)(lds + aoff[i]);
#pragma unroll
        for (int j = 0; j < 4; ++j) bf[j] = *(const short8*)(lds + boff[j]);
#pragma unroll
        for (int i = 0; i < 4; ++i)
#pragma unroll
            for (int j = 0; j < 4; ++j)
                acc[i][j] = __builtin_amdgcn_mfma_f32_16x16x32_bf16(af[i], bf[j], acc[i][j], 0, 0, 0);
    }

    if (QKV_EPI) {
#pragma unroll
        for (int j = 0; j < 4; ++j) {
            int col = bn*128 + wn*64 + j*16 + r;     // [0,2304)
            int t = col / CC;
            int rem = col - t*CC;
            int h = rem >> 6, d = rem & 63;
#pragma unroll
            for (int i = 0; i < 4; ++i) {
#pragma unroll
                for (int e = 0; e < 4; ++e) {
                    int m = bm*128 + wm*64 + i*16 + quad*4 + e;
                    int b = m >> 9, nrow = m & 511;
                    size_t idx = ((size_t)(b*HH + h)*NN + nrow)*HD + d;
                    float val = acc[i][j][e];
                    if (t == 2) {
                        vout[idx] = val;
                    } else {
                        unsigned short hi = f2bf(val);
                        unsigned short lo = f2bf(val - bf2f(hi));
                        if (t == 0) { qh[idx] = hi; ql[idx] = lo; }
                        else        { kh[idx] = hi; kl[idx] = lo; }
                    }
                }
            }
        }
    } else {
#pragma unroll
        for (int j = 0; j < 4; ++j) {
            int col = bn*128 + wn*64 + j*16 + r;
            float bv = bias[col];
#pragma unroll
            for (int i = 0; i < 4; ++i) {
#pragma unroll
                for (int e = 0; e < 4; ++e) {
                    int m = bm*128 + wm*64 + i*16 + quad*4 + e;
                    out[(size_t)m*NCOLS + col] = acc[i][j][e] + bv;
                }
            }
        }
    }
}

// ---------------------------------------------------------------------------
// MFMA scores + exact top-k + softmax.
// Block = one (b,h) x 64 rows; 4 waves, each wave = 16 rows x 512 cols.
// S = qh.khT + qh.klT + ql.khT  (3 terms x K=64 = 6 MFMA k-steps, 16x16x32).
// acc = 32 C-tiles/wave. K staged per 64-col chunk via global_load_lds w=16
// with octet XOR swizzle; A-frags cached in regs across chunks.
// C-layout: col=lane&15, row=quad*4+e -> row lives in one 16-lane quarter;
// radix select runs 4 rows/wave concurrently (per-quarter histograms).
// ---------------------------------------------------------------------------
__global__ __launch_bounds__(256) void attn_scores_k(
        const unsigned short* __restrict__ qh, const unsigned short* __restrict__ ql,
        const unsigned short* __restrict__ kh, const unsigned short* __restrict__ kl,
        const int* __restrict__ islast, float* __restrict__ attn) {

    __shared__ unsigned short qs[2][64][72];     // pad 72 -> b128 aligned, 2-way banks
    __shared__ char ks[16384];                   // [hl][64 cols][8 octs x 16B], swizzled
    __shared__ unsigned int hist[4][4][256];     // [wave][quad][bucket]

    const int bh = blockIdx.x >> 3;
    const int rb = blockIdx.x & 7;
    const int tid = threadIdx.x;
    const int wv = tid >> 6, lane = tid & 63;
    const int quad = lane >> 4, r = lane & 15;

    // ---- stage q (64 rows x 64, hi+lo) ----
    const unsigned short* gq[2] = { qh + ((size_t)bh*NN + rb*64)*HD,
                                    ql + ((size_t)bh*NN + rb*64)*HD };
#pragma unroll
    for (int i = 0; i < 4; ++i) {
        int s = tid + i*256;
        int hl = s >> 9, s2 = s & 511;
        int row = s2 >> 3, oct = s2 & 7;
        short8 val = *(const short8*)(gq[hl] + row*HD + oct*8);
        *(short8*)&qs[hl][row][oct*8] = val;
    }
    __syncthreads();

    // ---- A fragments cached: (term,half) -> src A = [h,h,l] ----
    short8 afr[6];
    {
        const int arow = wv*16 + r;
#pragma unroll
        for (int t = 0; t < 3; ++t) {
            int src = (t == 2) ? 1 : 0;
#pragma unroll
            for (int half = 0; half < 2; ++half)
                afr[t*2+half] = *(const short8*)&qs[src][arow][half*32 + quad*8];
        }
    }

    floatx4 acc[32];
#pragma unroll
    for (int ct = 0; ct < 32; ++ct) acc[ct] = (floatx4){0.f,0.f,0.f,0.f};

    const unsigned short* gk[2] = { kh + (size_t)bh*NN*HD, kl + (size_t)bh*NN*HD };

    // ---- phase 1: 8 chunks of 64 K-columns ----
    for (int ch = 0; ch < 8; ++ch) {
        __syncthreads();
#pragma unroll
        for (int i = 0; i < 4; ++i) {
            int s = tid + i*256;
            int hl = s >> 9, s2 = s & 511;
            int row = s2 >> 3, octp = s2 & 7;
            int oct = octp ^ (row & 7);
            const unsigned short* src = gk[hl] + (size_t)(ch*64 + row)*HD + oct*8;
            __builtin_amdgcn_global_load_lds(
                (const __attribute__((address_space(1))) unsigned int*)src,
                (__attribute__((address_space(3))) unsigned int*)(ks + (size_t)(i*256 + wv*64)*16),
                16, 0, 0);
        }
        asm volatile("s_waitcnt vmcnt(0)" ::: "memory");
        __syncthreads();

#pragma unroll
        for (int ctl = 0; ctl < 4; ++ctl) {
            const int ct = ch*4 + ctl;
            const int n = ctl*16 + r;
#pragma unroll
            for (int t = 0; t < 3; ++t) {
                const int srcB = (t == 1) ? 1 : 0;   // B terms: [h,l,h]
#pragma unroll
                for (int half = 0; half < 2; ++half) {
                    const int oct = (half*4 + quad) ^ (n & 7);
                    short8 bfr = *(const short8*)(ks + srcB*8192 + n*128 + oct*16);
                    acc[ct] = __builtin_amdgcn_mfma_f32_16x16x32_bf16(afr[t*2+half], bfr, acc[ct], 0, 0, 0);
                }
            }
        }
    }

#pragma unroll
    for (int ct = 0; ct < 32; ++ct) acc[ct] *= 0.125f;

    const int last = islast[0];

    // ---- phases 2+3: per reg-group e (4 rows/wave concurrently, one/quarter)
#pragma unroll
    for (int e = 0; e < 4; ++e) {
        unsigned int kth_key = 0u;
        if (!last) {
            unsigned int prefix = 0u;
            int kk = TOPK;
            for (int pass = 3; pass >= 0; --pass) {
                uint4 z = {0u,0u,0u,0u};
                *(uint4*)&hist[wv][quad][r*16]      = z;
                *(uint4*)&hist[wv][quad][r*16 + 4]  = z;
                *(uint4*)&hist[wv][quad][r*16 + 8]  = z;
                *(uint4*)&hist[wv][quad][r*16 + 12] = z;
                asm volatile("s_waitcnt lgkmcnt(0)" ::: "memory");
                const unsigned int maskhi = (pass == 3) ? 0u
                                          : (0xFFFFFFFFu << ((pass + 1) * 8));
                const int sh = pass * 8;
#pragma unroll
                for (int ct = 0; ct < 32; ++ct) {
                    unsigned int u = __float_as_uint(acc[ct][e]);
                    u = (u & 0x80000000u) ? ~u : (u | 0x80000000u);
                    if ((u & maskhi) == (prefix & maskhi))
                        atomicAdd(&hist[wv][quad][(u >> sh) & 255u], 1u);
                }
                asm volatile("s_waitcnt lgkmcnt(0)" ::: "memory");
                // chunk sums: lane r covers buckets [240-16r, 255-16r]
                const int cb = 240 - 16*r;
                uint4 h0 = *(uint4*)&hist[wv][quad][cb];
                uint4 h1 = *(uint4*)&hist[wv][quad][cb + 4];
                uint4 h2 = *(uint4*)&hist[wv][quad][cb + 8];
                uint4 h3 = *(uint4*)&hist[wv][quad][cb + 12];
                unsigned int p = h0.x+h0.y+h0.z+h0.w + h1.x+h1.y+h1.z+h1.w
                               + h2.x+h2.y+h2.z+h2.w + h3.x+h3.y+h3.z+h3.w;
                unsigned int D = p;               // prefix over lanes (desc buckets)
#pragma unroll
                for (int off = 1; off < 16; off <<= 1) {
                    unsigned int tt = __shfl_up(D, off);
                    if (r >= off) D += tt;
                }
                unsigned long long bal = __ballot((int)D >= kk);
                unsigned int m16 = (unsigned int)(bal >> (quad*16)) & 0xFFFFu;
                int wl = __ffs(m16) - 1;          // first lane (highest chunk)
                unsigned int Dw = __shfl(D, quad*16 + wl);
                unsigned int pw = __shfl(p, quad*16 + wl);
                int cum_before = (int)(Dw - pw);
                // within winner chunk: lane r holds bucket (240-16*wl + r)
                unsigned int hb = hist[wv][quad][240 - 16*wl + r];
                unsigned int T = hb;              // suffix sum over r
#pragma unroll
                for (int off = 1; off < 16; off <<= 1) {
                    unsigned int tt = __shfl_down(T, off);
                    if (r + off < 16) T += tt;
                }
                unsigned int cge = (unsigned int)cum_before + T;
                unsigned long long bal2 = __ballot((int)cge >= kk);
                unsigned int m2 = (unsigned int)(bal2 >> (quad*16)) & 0xFFFFu;
                int rs = 31 - __clz(m2);          // largest r with cge>=kk
                unsigned int Ts = __shfl(T,  quad*16 + rs);
                unsigned int hs = __shfl(hb, quad*16 + rs);
                kk -= (int)((unsigned int)cum_before + Ts - hs);
                prefix |= (unsigned int)(240 - 16*wl + rs) << sh;
            }
            kth_key = prefix;
        }

        // masked softmax over this row (16-lane quarter x 32 tiles)
        float mx = -INFINITY;
#pragma unroll
        for (int ct = 0; ct < 32; ++ct) mx = fmaxf(mx, acc[ct][e]);
#pragma unroll
        for (int off = 8; off >= 1; off >>= 1) mx = fmaxf(mx, __shfl_xor(mx, off));
        float sum = 0.f;
#pragma unroll
        for (int ct = 0; ct < 32; ++ct) {
            unsigned int u = __float_as_uint(acc[ct][e]);
            u = (u & 0x80000000u) ? ~u : (u | 0x80000000u);
            float ev = (last || u >= kth_key) ? __expf(acc[ct][e] - mx) : 0.f;
            acc[ct][e] = ev;
            sum += ev;
        }
#pragma unroll
        for (int off = 8; off >= 1; off >>= 1) sum += __shfl_xor(sum, off);
        const float inv = 1.f / sum;
        float* arow = attn + ((size_t)bh*NN + rb*64 + wv*16 + quad*4 + e) * NN;
#pragma unroll
        for (int ct = 0; ct < 32; ++ct) arow[ct*16 + r] = acc[ct][e] * inv;
    }
}

// ---------------------------------------------------------------------------
// O = P @ V per head; epilogue writes split-bf16 o [hi|hi|lo] into Ao.
// ---------------------------------------------------------------------------
__global__ __launch_bounds__(256) void attn_pv_k(const float* __restrict__ attn,
                                                 const float* __restrict__ v,
                                                 unsigned short* __restrict__ Ao) {
    __shared__ float ps[32][68];
    __shared__ float vs[32][68];
    const int blk = blockIdx.x;
    const int bh  = blk >> 3;
    const int nt  = blk & 7;
    const int b = bh / HH, h = bh % HH;
    const int tid = threadIdx.x;
    const int tx = tid & 15, ty = tid >> 4;
    const float* pb = attn + ((size_t)bh*NN + nt*64) * NN;
    const float* vb = v + (size_t)bh*NN*HD;
    float acc[4][4] = {};
    for (int k0 = 0; k0 < NN; k0 += 32) {
        const int pr = tid >> 3;
        const int pc = (tid & 7) * 4;
        float4 p0 = *(const float4*)(pb + (size_t)pr*NN + k0 + pc);
        float4 p1 = *(const float4*)(pb + (size_t)(pr + 32)*NN + k0 + pc);
        const int vr = tid >> 4;
        const int vc = (tid & 15) * 4;
        float4 v0 = *(const float4*)(vb + (size_t)(k0 + vr)*HD + vc);
        float4 v1 = *(const float4*)(vb + (size_t)(k0 + vr + 16)*HD + vc);
        __syncthreads();
        ps[pc+0][pr] = p0.x; ps[pc+1][pr] = p0.y; ps[pc+2][pr] = p0.z; ps[pc+3][pr] = p0.w;
        ps[pc+0][pr+32] = p1.x; ps[pc+1][pr+32] = p1.y; ps[pc+2][pr+32] = p1.z; ps[pc+3][pr+32] = p1.w;
        *(float4*)&vs[vr][vc]      = v0;
        *(float4*)&vs[vr+16][vc]   = v1;
        __syncthreads();
#pragma unroll
        for (int k = 0; k < 32; ++k) {
            float4 a4 = *(const float4*)&ps[k][ty*4];
            float4 b4 = *(const float4*)&vs[k][tx*4];
            float aa[4] = {a4.x, a4.y, a4.z, a4.w};
            float bb[4] = {b4.x, b4.y, b4.z, b4.w};
#pragma unroll
            for (int i = 0; i < 4; ++i)
#pragma unroll
                for (int j = 0; j < 4; ++j)
                    acc[i][j] += aa[i] * bb[j];
        }
    }
#pragma unroll
    for (int i = 0; i < 4; ++i) {
        int n = nt*64 + ty*4 + i;
        int mrow = b*NN + n;
        int c = h*HD + tx*4;
        ushort4 hi, lo;
        hi.x = f2bf(acc[i][0]); lo.x = f2bf(acc[i][0] - bf2f(hi.x));
        hi.y = f2bf(acc[i][1]); lo.y = f2bf(acc[i][1] - bf2f(hi.y));
        hi.z = f2bf(acc[i][2]); lo.z = f2bf(acc[i][2] - bf2f(hi.z));
        hi.w = f2bf(acc[i][3]); lo.w = f2bf(acc[i][3] - bf2f(hi.w));
        unsigned short* base = Ao + (size_t)mrow*KC + c;
        *(ushort4*)(base)        = hi;
        *(ushort4*)(base + CC)   = hi;
        *(ushort4*)(base + 2*CC) = lo;
    }
}

// ---------------------------------------------------------------------------
extern "C" void kernel_launch(void* const* d_in, const int* in_sizes, int n_in,
                              void* d_out, int out_size, void* d_ws, size_t ws_size,
                              hipStream_t stream) {
    const float* x      = (const float*)d_in[0];
    const float* qkv_w  = (const float*)d_in[1];
    const float* proj_w = (const float*)d_in[2];
    const float* proj_b = (const float*)d_in[3];
    const int*   islast = (const int*)d_in[4];

    float* out  = (float*)d_out;                       // [B,N,C]
    float* attn = out + (size_t)BB*NN*CC;              // [B,H,N,N]

    float* ws = (float*)d_ws;
    float* v  = ws;                                              // [B,H,N,hd] fp32
    unsigned short* qhp = (unsigned short*)(ws + (size_t)QKV_ELEMS);
    unsigned short* qlp = qhp + (size_t)QKV_ELEMS;
    unsigned short* khp = qlp + (size_t)QKV_ELEMS;
    unsigned short* klp = khp + (size_t)QKV_ELEMS;
    unsigned short* Asp   = klp + (size_t)QKV_ELEMS;   // [4096][2304]
    unsigned short* Bqkv  = Asp  + (size_t)4096*KC;    // [2304][2304]
    unsigned short* Bproj = Bqkv + (size_t)2304*KC;    // [768][2304]

    split_k<true> <<<dim3(4096*CC/4/256), 256, 0, stream>>>(x,      Asp,   4096*CC/4);
    split_k<false><<<dim3(2304*CC/4/256), 256, 0, stream>>>(qkv_w,  Bqkv,  2304*CC/4);
    split_k<false><<<dim3(CC*CC/4/256),   256, 0, stream>>>(proj_w, Bproj, CC*CC/4);

    gemm_split<0, true>  <<<dim3(32, 18), 256, 0, stream>>>(Asp, Bqkv, nullptr, nullptr,
                                                            qhp, qlp, khp, klp, v);
    attn_scores_k        <<<dim3(96*8),   256, 0, stream>>>(qhp, qlp, khp, klp, islast, attn);
    attn_pv_k            <<<dim3(96*8),   256, 0, stream>>>(attn, v, Asp);
    gemm_split<CC, false><<<dim3(32, 6),  256, 0, stream>>>(Asp, Bproj, proj_b, out,
                                                            nullptr, nullptr, nullptr, nullptr, nullptr);
}

// Round 5
// 393.737 us; speedup vs baseline: 1.1930x; 1.1930x over previous
//
#include <hip/hip_runtime.h>
#include <math.h>

#define BB 8
#define NN 512
#define CC 768
#define HH 12
#define HD 64
#define TOPK 90
#define QKV_ELEMS (BB*HH*NN*HD)   // 3145728 elements per q/k/v tensor
#define KC 2304                   // split-K: 3*768

typedef __attribute__((ext_vector_type(8))) short short8;   // 8 bf16 = 4 VGPR
typedef __attribute__((ext_vector_type(4))) float floatx4;  // MFMA C/D

__device__ inline unsigned short f2bf(float f) {
    unsigned int u = __float_as_uint(f);
    u += 0x7FFFu + ((u >> 16) & 1u);           // RNE
    return (unsigned short)(u >> 16);
}
__device__ inline float bf2f(unsigned short h) {
    return __uint_as_float(((unsigned int)h) << 16);
}

// ---------------------------------------------------------------------------
// Split kernels: fp32 [rows][768] -> bf16 [rows][2304].
// IS_A: blocks [hi | hi | lo]; !IS_A: blocks [hi | lo | hi]  (hh+hl+lh).
// ---------------------------------------------------------------------------
template<bool IS_A>
__global__ __launch_bounds__(256) void split_k(const float* __restrict__ in,
                                               unsigned short* __restrict__ o2,
                                               int total) {
    int idx = blockIdx.x * 256 + threadIdx.x;
    if (idx >= total) return;
    int e = idx * 4;
    int m = e / CC, kk = e - m * CC;
    float4 f = *(const float4*)(in + e);
    ushort4 hi, lo;
    hi.x = f2bf(f.x); lo.x = f2bf(f.x - bf2f(hi.x));
    hi.y = f2bf(f.y); lo.y = f2bf(f.y - bf2f(hi.y));
    hi.z = f2bf(f.z); lo.z = f2bf(f.z - bf2f(hi.z));
    hi.w = f2bf(f.w); lo.w = f2bf(f.w - bf2f(hi.w));
    unsigned short* base = o2 + (size_t)m * KC + kk;
    *(ushort4*)(base)        = hi;
    *(ushort4*)(base + CC)   = IS_A ? hi : lo;
    *(ushort4*)(base + 2*CC) = IS_A ? lo : hi;
}

// ---------------------------------------------------------------------------
// Split-bf16 MFMA GEMM. QKV_EPI: q,k -> split bf16 planes [B,H,N,hd];
// v -> TRANSPOSED fp32 vt[B,H,hd,N] (coalesced float4 over rows).
// Else: out[m][NCOLS] + bias.
// ---------------------------------------------------------------------------
template<int NCOLS, bool QKV_EPI>
__global__ __launch_bounds__(256) void gemm_split(const unsigned short* __restrict__ A,
                                                  const unsigned short* __restrict__ Bm,
                                                  const float* __restrict__ bias,
                                                  float* __restrict__ out,
                                                  unsigned short* __restrict__ qh,
                                                  unsigned short* __restrict__ ql,
                                                  unsigned short* __restrict__ kh,
                                                  unsigned short* __restrict__ kl,
                                                  float* __restrict__ vt) {
    __shared__ char lds[16384];
    const int bm = blockIdx.x, bn = blockIdx.y;
    const int tid  = threadIdx.x;
    const int wave = tid >> 6, lane = tid & 63;
    const int wm = wave >> 1, wn = wave & 1;
    const int quad = lane >> 4, r = lane & 15;

    const int cA0 = tid, cA1 = tid + 256;
    const int mA0 = cA0 >> 2, oA0 = (cA0 & 3) ^ ((mA0 >> 1) & 3);
    const int mA1 = cA1 >> 2, oA1 = (cA1 & 3) ^ ((mA1 >> 1) & 3);
    const unsigned short* gA0 = A  + (size_t)(bm*128 + mA0) * KC + oA0*8;
    const unsigned short* gA1 = A  + (size_t)(bm*128 + mA1) * KC + oA1*8;
    const unsigned short* gB0 = Bm + (size_t)(bn*128 + mA0) * KC + oA0*8;
    const unsigned short* gB1 = Bm + (size_t)(bn*128 + mA1) * KC + oA1*8;
    char* lA0 = lds + (wave*64)*16;
    char* lA1 = lds + (256 + wave*64)*16;
    char* lB0 = lds + 8192 + (wave*64)*16;
    char* lB1 = lds + 8192 + (256 + wave*64)*16;

    const int octsel = quad ^ ((r >> 1) & 3);
    int aoff[4], boff[4];
#pragma unroll
    for (int i = 0; i < 4; ++i) {
        aoff[i] = ((wm*64 + i*16 + r)*4 + octsel) * 16;
        boff[i] = 8192 + ((wn*64 + i*16 + r)*4 + octsel) * 16;
    }

    floatx4 acc[4][4];
#pragma unroll
    for (int i = 0; i < 4; ++i)
#pragma unroll
        for (int j = 0; j < 4; ++j)
            acc[i][j] = (floatx4){0.f, 0.f, 0.f, 0.f};

    for (int it = 0; it < KC/32; ++it) {
        __syncthreads();
        __builtin_amdgcn_global_load_lds((const __attribute__((address_space(1))) unsigned int*)gA0,
                                         (__attribute__((address_space(3))) unsigned int*)lA0, 16, 0, 0);
        __builtin_amdgcn_global_load_lds((const __attribute__((address_space(1))) unsigned int*)gA1,
                                         (__attribute__((address_space(3))) unsigned int*)lA1, 16, 0, 0);
        __builtin_amdgcn_global_load_lds((const __attribute__((address_space(1))) unsigned int*)gB0,
                                         (__attribute__((address_space(3))) unsigned int*)lB0, 16, 0, 0);
        __builtin_amdgcn_global_load_lds((const __attribute__((address_space(1))) unsigned int*)gB1,
                                         (__attribute__((address_space(3))) unsigned int*)lB1, 16, 0, 0);
        gA0 += 32; gA1 += 32; gB0 += 32; gB1 += 32;
        asm volatile("s_waitcnt vmcnt(0)" ::: "memory");
        __syncthreads();

        short8 af[4], bf[4];
#pragma unroll
        for (int i = 0; i < 4; ++i) af[i] = *(const short8*)(lds + aoff[i]);
#pragma unroll
        for (int j = 0; j < 4; ++j) bf[j] = *(const short8*)(lds + boff[j]);
#pragma unroll
        for (int i = 0; i < 4; ++i)
#pragma unroll
            for (int j = 0; j < 4; ++j)
                acc[i][j] = __builtin_amdgcn_mfma_f32_16x16x32_bf16(af[i], bf[j], acc[i][j], 0, 0, 0);
    }

    if (QKV_EPI) {
#pragma unroll
        for (int j = 0; j < 4; ++j) {
            int col = bn*128 + wn*64 + j*16 + r;     // [0,2304)
            int t = col / CC;
            int rem = col - t*CC;
            int h = rem >> 6, d = rem & 63;
            if (t == 2) {
                // v transposed: vt[(bh*64+d)*512 + n], float4 over 4 rows
#pragma unroll
                for (int i = 0; i < 4; ++i) {
                    int m0 = bm*128 + wm*64 + i*16 + quad*4;
                    int b = m0 >> 9, n0 = m0 & 511;
                    float4 o4 = {acc[i][j][0], acc[i][j][1], acc[i][j][2], acc[i][j][3]};
                    *(float4*)(vt + ((size_t)((b*HH + h)*HD + d))*NN + n0) = o4;
                }
            } else {
                unsigned short* ph = (t == 0) ? qh : kh;
                unsigned short* pl = (t == 0) ? ql : kl;
#pragma unroll
                for (int i = 0; i < 4; ++i) {
#pragma unroll
                    for (int e = 0; e < 4; ++e) {
                        int m = bm*128 + wm*64 + i*16 + quad*4 + e;
                        int b = m >> 9, nrow = m & 511;
                        size_t idx = ((size_t)(b*HH + h)*NN + nrow)*HD + d;
                        float val = acc[i][j][e];
                        unsigned short hi = f2bf(val);
                        ph[idx] = hi;
                        pl[idx] = f2bf(val - bf2f(hi));
                    }
                }
            }
        }
    } else {
#pragma unroll
        for (int j = 0; j < 4; ++j) {
            int col = bn*128 + wn*64 + j*16 + r;
            float bv = bias[col];
#pragma unroll
            for (int i = 0; i < 4; ++i) {
#pragma unroll
                for (int e = 0; e < 4; ++e) {
                    int m = bm*128 + wm*64 + i*16 + quad*4 + e;
                    out[(size_t)m*NCOLS + col] = acc[i][j][e] + bv;
                }
            }
        }
    }
}

// ---------------------------------------------------------------------------
// MFMA scores + exact top-k + softmax.  Phase 1 as round 4 (verified).
// Top-k: register-only bit-serial radix select per row (16-lane quarter,
// 32 values/lane).  No LDS histogram, no atomics.  Early exit when
// |candidates|==kk (kth = min) or kk==1 (kth = max); ~14-18 bits typical.
// ---------------------------------------------------------------------------
__global__ __launch_bounds__(256) void attn_scores_k(
        const unsigned short* __restrict__ qh, const unsigned short* __restrict__ ql,
        const unsigned short* __restrict__ kh, const unsigned short* __restrict__ kl,
        const int* __restrict__ islast, float* __restrict__ attn) {

    __shared__ unsigned short qs[2][64][72];
    __shared__ char ks[16384];

    const int bh = blockIdx.x >> 3;
    const int rb = blockIdx.x & 7;
    const int tid = threadIdx.x;
    const int wv = tid >> 6, lane = tid & 63;
    const int quad = lane >> 4, r = lane & 15;

    const unsigned short* gq[2] = { qh + ((size_t)bh*NN + rb*64)*HD,
                                    ql + ((size_t)bh*NN + rb*64)*HD };
#pragma unroll
    for (int i = 0; i < 4; ++i) {
        int s = tid + i*256;
        int hl = s >> 9, s2 = s & 511;
        int row = s2 >> 3, oct = s2 & 7;
        short8 val = *(const short8*)(gq[hl] + row*HD + oct*8);
        *(short8*)&qs[hl][row][oct*8] = val;
    }
    __syncthreads();

    short8 afr[6];
    {
        const int arow = wv*16 + r;
#pragma unroll
        for (int t = 0; t < 3; ++t) {
            int src = (t == 2) ? 1 : 0;
#pragma unroll
            for (int half = 0; half < 2; ++half)
                afr[t*2+half] = *(const short8*)&qs[src][arow][half*32 + quad*8];
        }
    }

    floatx4 acc[32];
#pragma unroll
    for (int ct = 0; ct < 32; ++ct) acc[ct] = (floatx4){0.f,0.f,0.f,0.f};

    const unsigned short* gk[2] = { kh + (size_t)bh*NN*HD, kl + (size_t)bh*NN*HD };

    for (int ch = 0; ch < 8; ++ch) {
        __syncthreads();
#pragma unroll
        for (int i = 0; i < 4; ++i) {
            int s = tid + i*256;
            int hl = s >> 9, s2 = s & 511;
            int row = s2 >> 3, octp = s2 & 7;
            int oct = octp ^ (row & 7);
            const unsigned short* src = gk[hl] + (size_t)(ch*64 + row)*HD + oct*8;
            __builtin_amdgcn_global_load_lds(
                (const __attribute__((address_space(1))) unsigned int*)src,
                (__attribute__((address_space(3))) unsigned int*)(ks + (size_t)(i*256 + wv*64)*16),
                16, 0, 0);
        }
        asm volatile("s_waitcnt vmcnt(0)" ::: "memory");
        __syncthreads();

#pragma unroll
        for (int ctl = 0; ctl < 4; ++ctl) {
            const int ct = ch*4 + ctl;
            const int n = ctl*16 + r;
#pragma unroll
            for (int t = 0; t < 3; ++t) {
                const int srcB = (t == 1) ? 1 : 0;
#pragma unroll
                for (int half = 0; half < 2; ++half) {
                    const int oct = (half*4 + quad) ^ (n & 7);
                    short8 bfr = *(const short8*)(ks + srcB*8192 + n*128 + oct*16);
                    acc[ct] = __builtin_amdgcn_mfma_f32_16x16x32_bf16(afr[t*2+half], bfr, acc[ct], 0, 0, 0);
                }
            }
        }
    }

#pragma unroll
    for (int ct = 0; ct < 32; ++ct) acc[ct] *= 0.125f;

    const int last = islast[0];

#pragma unroll
    for (int e = 0; e < 4; ++e) {
        // in-place ordered-key transform (bijective)
#pragma unroll
        for (int ct = 0; ct < 32; ++ct) {
            unsigned int t = __float_as_uint(acc[ct][e]);
            t = (t & 0x80000000u) ? ~t : (t | 0x80000000u);
            acc[ct][e] = __uint_as_float(t);
        }
        unsigned int key = 0u;
        if (!last) {
            unsigned int am = 0xFFFFFFFFu;   // active candidates (bit per ct)
            int kk = TOPK, cntA = 512, done = 0;
            for (int bit = 31; bit >= 0; --bit) {
                if (!done) {
                    unsigned int m1 = 0u;
#pragma unroll
                    for (int ct = 0; ct < 32; ++ct)
                        m1 |= ((__float_as_uint(acc[ct][e]) >> bit) & 1u) << ct;
                    int c1 = __popc(am & m1);
                    c1 += __shfl_xor(c1, 1);
                    c1 += __shfl_xor(c1, 2);
                    c1 += __shfl_xor(c1, 4);
                    c1 += __shfl_xor(c1, 8);
                    if (kk <= c1) { am &= m1; cntA = c1; }
                    else          { kk -= c1; am &= ~m1; cntA -= c1; }
                    done = (cntA == kk) | (kk == 1);
                }
                if (__ballot(!done) == 0ull) break;
            }
            unsigned int mn = 0xFFFFFFFFu, mx = 0u;
#pragma unroll
            for (int ct = 0; ct < 32; ++ct) {
                unsigned int uu = __float_as_uint(acc[ct][e]);
                if ((am >> ct) & 1u) { mn = mn < uu ? mn : uu; mx = mx > uu ? mx : uu; }
            }
#pragma unroll
            for (int off = 1; off <= 8; off <<= 1) {
                unsigned int mns = __shfl_xor(mn, off), mxs = __shfl_xor(mx, off);
                mn = mn < mns ? mn : mns; mx = mx > mxs ? mx : mxs;
            }
            key = (kk == 1) ? mx : mn;       // kk==1: kth = max(A); else min(A)
        }

        unsigned int umx = 0u;
#pragma unroll
        for (int ct = 0; ct < 32; ++ct) {
            unsigned int uu = __float_as_uint(acc[ct][e]);
            umx = umx > uu ? umx : uu;
        }
#pragma unroll
        for (int off = 1; off <= 8; off <<= 1) {
            unsigned int t2 = __shfl_xor(umx, off);
            umx = umx > t2 ? umx : t2;
        }
        float fmx = __uint_as_float((umx & 0x80000000u) ? (umx & 0x7FFFFFFFu) : ~umx);
        float sum = 0.f;
#pragma unroll
        for (int ct = 0; ct < 32; ++ct) {
            unsigned int uu = __float_as_uint(acc[ct][e]);
            float f = __uint_as_float((uu & 0x80000000u) ? (uu & 0x7FFFFFFFu) : ~uu);
            float ev = (last || uu >= key) ? __expf(f - fmx) : 0.f;
            acc[ct][e] = ev;
            sum += ev;
        }
#pragma unroll
        for (int off = 1; off <= 8; off <<= 1) sum += __shfl_xor(sum, off);
        const float inv = 1.f / sum;
        float* arow = attn + ((size_t)bh*NN + rb*64 + wv*16 + quad*4 + e) * NN;
#pragma unroll
        for (int ct = 0; ct < 32; ++ct) arow[ct*16 + r] = acc[ct][e] * inv;
    }
}

// ---------------------------------------------------------------------------
// MFMA PV:  O[64 x 64] = P[64 x 512] @ V[512 x 64] per (head, row-tile).
// P bf16 single (prob in [0,1], err ~2^-9*p: negligible); V = vh + vl from
// transposed fp32 vt.  Epilogue writes split-bf16 o [hi|hi|lo] into Ao.
// ---------------------------------------------------------------------------
__global__ __launch_bounds__(256) void attn_pv_k(const float* __restrict__ attn,
                                                 const float* __restrict__ vt,
                                                 unsigned short* __restrict__ Ao) {
    __shared__ unsigned short pls[64][72];
    __shared__ unsigned short vhs[64][72];
    __shared__ unsigned short vls[64][72];

    const int blk = blockIdx.x;
    const int bh  = blk >> 3;
    const int rb  = blk & 7;
    const int b = bh / HH, h = bh % HH;
    const int tid = threadIdx.x;
    const int wv = tid >> 6, lane = tid & 63;
    const int quad = lane >> 4, r = lane & 15;

    const int sm = tid >> 2;           // staging row 0..63
    const int sk = (tid & 3) * 16;     // staging col base
    const float* prow = attn + ((size_t)bh*NN + rb*64 + sm) * NN + sk;
    const float* vrow = vt + ((size_t)bh*HD + sm) * NN + sk;

    floatx4 accO[4];
#pragma unroll
    for (int j = 0; j < 4; ++j) accO[j] = (floatx4){0.f,0.f,0.f,0.f};

    for (int ch = 0; ch < 8; ++ch) {
        float pv[16], vv[16];
#pragma unroll
        for (int x = 0; x < 4; ++x) {
            *(float4*)&pv[x*4] = *(const float4*)(prow + ch*64 + x*4);
            *(float4*)&vv[x*4] = *(const float4*)(vrow + ch*64 + x*4);
        }
        __syncthreads();   // readers of previous chunk done
        unsigned short tp[16], th[16], tl[16];
#pragma unroll
        for (int x = 0; x < 16; ++x) {
            tp[x] = f2bf(pv[x]);
            th[x] = f2bf(vv[x]);
            tl[x] = f2bf(vv[x] - bf2f(th[x]));
        }
        *(short8*)&pls[sm][sk]   = *(short8*)&tp[0];
        *(short8*)&pls[sm][sk+8] = *(short8*)&tp[8];
        *(short8*)&vhs[sm][sk]   = *(short8*)&th[0];
        *(short8*)&vhs[sm][sk+8] = *(short8*)&th[8];
        *(short8*)&vls[sm][sk]   = *(short8*)&tl[0];
        *(short8*)&vls[sm][sk+8] = *(short8*)&tl[8];
        __syncthreads();

#pragma unroll
        for (int kb = 0; kb < 2; ++kb) {
            short8 af = *(const short8*)&pls[wv*16 + r][kb*32 + quad*8];
#pragma unroll
            for (int j = 0; j < 4; ++j) {
                short8 bh8 = *(const short8*)&vhs[j*16 + r][kb*32 + quad*8];
                short8 bl8 = *(const short8*)&vls[j*16 + r][kb*32 + quad*8];
                accO[j] = __builtin_amdgcn_mfma_f32_16x16x32_bf16(af, bh8, accO[j], 0, 0, 0);
                accO[j] = __builtin_amdgcn_mfma_f32_16x16x32_bf16(af, bl8, accO[j], 0, 0, 0);
            }
        }
    }

#pragma unroll
    for (int j = 0; j < 4; ++j) {
        int d = j*16 + r;
#pragma unroll
        for (int e = 0; e < 4; ++e) {
            int n = rb*64 + wv*16 + quad*4 + e;
            size_t mrow = (size_t)b*NN + n;
            float val = accO[j][e];
            unsigned short hi = f2bf(val);
            unsigned short lo = f2bf(val - bf2f(hi));
            unsigned short* base = Ao + mrow*KC + h*HD + d;
            base[0] = hi; base[CC] = hi; base[2*CC] = lo;
        }
    }
}

// ---------------------------------------------------------------------------
extern "C" void kernel_launch(void* const* d_in, const int* in_sizes, int n_in,
                              void* d_out, int out_size, void* d_ws, size_t ws_size,
                              hipStream_t stream) {
    const float* x      = (const float*)d_in[0];
    const float* qkv_w  = (const float*)d_in[1];
    const float* proj_w = (const float*)d_in[2];
    const float* proj_b = (const float*)d_in[3];
    const int*   islast = (const int*)d_in[4];

    float* out  = (float*)d_out;                       // [B,N,C]
    float* attn = out + (size_t)BB*NN*CC;              // [B,H,N,N]

    float* ws = (float*)d_ws;
    float* vt = ws;                                    // [B,H,hd,N] fp32 (transposed v)
    unsigned short* qhp = (unsigned short*)(ws + (size_t)QKV_ELEMS);
    unsigned short* qlp = qhp + (size_t)QKV_ELEMS;
    unsigned short* khp = qlp + (size_t)QKV_ELEMS;
    unsigned short* klp = khp + (size_t)QKV_ELEMS;
    unsigned short* Asp   = klp + (size_t)QKV_ELEMS;   // [4096][2304]
    unsigned short* Bqkv  = Asp  + (size_t)4096*KC;    // [2304][2304]
    unsigned short* Bproj = Bqkv + (size_t)2304*KC;    // [768][2304]

    split_k<true> <<<dim3(4096*CC/4/256), 256, 0, stream>>>(x,      Asp,   4096*CC/4);
    split_k<false><<<dim3(2304*CC/4/256), 256, 0, stream>>>(qkv_w,  Bqkv,  2304*CC/4);
    split_k<false><<<dim3(CC*CC/4/256),   256, 0, stream>>>(proj_w, Bproj, CC*CC/4);

    gemm_split<0, true>  <<<dim3(32, 18), 256, 0, stream>>>(Asp, Bqkv, nullptr, nullptr,
                                                            qhp, qlp, khp, klp, vt);
    attn_scores_k        <<<dim3(96*8),   256, 0, stream>>>(qhp, qlp, khp, klp, islast, attn);
    attn_pv_k            <<<dim3(96*8),   256, 0, stream>>>(attn, vt, Asp);
    gemm_split<CC, false><<<dim3(32, 6),  256, 0, stream>>>(Asp, Bproj, proj_b, out,
                                                            nullptr, nullptr, nullptr, nullptr, nullptr);
}

// Round 6
// 366.225 us; speedup vs baseline: 1.2827x; 1.0751x over previous
//
#include <hip/hip_runtime.h>
#include <math.h>

#define BB 8
#define NN 512
#define CC 768
#define HH 12
#define HD 64
#define TOPK 90
#define QKV_ELEMS (BB*HH*NN*HD)   // 3145728 elements per q/k/v tensor
#define KC 2304                   // split-K: 3*768

typedef __attribute__((ext_vector_type(8))) short short8;   // 8 bf16 = 4 VGPR
typedef __attribute__((ext_vector_type(4))) float floatx4;  // MFMA C/D

__device__ inline unsigned short f2bf(float f) {
    unsigned int u = __float_as_uint(f);
    u += 0x7FFFu + ((u >> 16) & 1u);           // RNE
    return (unsigned short)(u >> 16);
}
__device__ inline float bf2f(unsigned short h) {
    return __uint_as_float(((unsigned int)h) << 16);
}

// ---------------------------------------------------------------------------
// Split kernels: fp32 [rows][768] -> bf16 [rows][2304].
// IS_A: blocks [hi | hi | lo]; !IS_A: blocks [hi | lo | hi]  (hh+hl+lh).
// ---------------------------------------------------------------------------
template<bool IS_A>
__global__ __launch_bounds__(256) void split_k(const float* __restrict__ in,
                                               unsigned short* __restrict__ o2,
                                               int total) {
    int idx = blockIdx.x * 256 + threadIdx.x;
    if (idx >= total) return;
    int e = idx * 4;
    int m = e / CC, kk = e - m * CC;
    float4 f = *(const float4*)(in + e);
    ushort4 hi, lo;
    hi.x = f2bf(f.x); lo.x = f2bf(f.x - bf2f(hi.x));
    hi.y = f2bf(f.y); lo.y = f2bf(f.y - bf2f(hi.y));
    hi.z = f2bf(f.z); lo.z = f2bf(f.z - bf2f(hi.z));
    hi.w = f2bf(f.w); lo.w = f2bf(f.w - bf2f(hi.w));
    unsigned short* base = o2 + (size_t)m * KC + kk;
    *(ushort4*)(base)        = hi;
    *(ushort4*)(base + CC)   = IS_A ? hi : lo;
    *(ushort4*)(base + 2*CC) = IS_A ? lo : hi;
}

// ---------------------------------------------------------------------------
// Split-bf16 MFMA GEMM. QKV_EPI: q,k -> split bf16 planes [B,H,N,hd];
// v -> TRANSPOSED fp32 vt[B,H,hd,N].  Else: out[m][NCOLS] + bias.
// ---------------------------------------------------------------------------
template<int NCOLS, bool QKV_EPI>
__global__ __launch_bounds__(256) void gemm_split(const unsigned short* __restrict__ A,
                                                  const unsigned short* __restrict__ Bm,
                                                  const float* __restrict__ bias,
                                                  float* __restrict__ out,
                                                  unsigned short* __restrict__ qh,
                                                  unsigned short* __restrict__ ql,
                                                  unsigned short* __restrict__ kh,
                                                  unsigned short* __restrict__ kl,
                                                  float* __restrict__ vt) {
    __shared__ char lds[16384];
    const int bm = blockIdx.x, bn = blockIdx.y;
    const int tid  = threadIdx.x;
    const int wave = tid >> 6, lane = tid & 63;
    const int wm = wave >> 1, wn = wave & 1;
    const int quad = lane >> 4, r = lane & 15;

    const int cA0 = tid, cA1 = tid + 256;
    const int mA0 = cA0 >> 2, oA0 = (cA0 & 3) ^ ((mA0 >> 1) & 3);
    const int mA1 = cA1 >> 2, oA1 = (cA1 & 3) ^ ((mA1 >> 1) & 3);
    const unsigned short* gA0 = A  + (size_t)(bm*128 + mA0) * KC + oA0*8;
    const unsigned short* gA1 = A  + (size_t)(bm*128 + mA1) * KC + oA1*8;
    const unsigned short* gB0 = Bm + (size_t)(bn*128 + mA0) * KC + oA0*8;
    const unsigned short* gB1 = Bm + (size_t)(bn*128 + mA1) * KC + oA1*8;
    char* lA0 = lds + (wave*64)*16;
    char* lA1 = lds + (256 + wave*64)*16;
    char* lB0 = lds + 8192 + (wave*64)*16;
    char* lB1 = lds + 8192 + (256 + wave*64)*16;

    const int octsel = quad ^ ((r >> 1) & 3);
    int aoff[4], boff[4];
#pragma unroll
    for (int i = 0; i < 4; ++i) {
        aoff[i] = ((wm*64 + i*16 + r)*4 + octsel) * 16;
        boff[i] = 8192 + ((wn*64 + i*16 + r)*4 + octsel) * 16;
    }

    floatx4 acc[4][4];
#pragma unroll
    for (int i = 0; i < 4; ++i)
#pragma unroll
        for (int j = 0; j < 4; ++j)
            acc[i][j] = (floatx4){0.f, 0.f, 0.f, 0.f};

    for (int it = 0; it < KC/32; ++it) {
        __syncthreads();
        __builtin_amdgcn_global_load_lds((const __attribute__((address_space(1))) unsigned int*)gA0,
                                         (__attribute__((address_space(3))) unsigned int*)lA0, 16, 0, 0);
        __builtin_amdgcn_global_load_lds((const __attribute__((address_space(1))) unsigned int*)gA1,
                                         (__attribute__((address_space(3))) unsigned int*)lA1, 16, 0, 0);
        __builtin_amdgcn_global_load_lds((const __attribute__((address_space(1))) unsigned int*)gB0,
                                         (__attribute__((address_space(3))) unsigned int*)lB0, 16, 0, 0);
        __builtin_amdgcn_global_load_lds((const __attribute__((address_space(1))) unsigned int*)gB1,
                                         (__attribute__((address_space(3))) unsigned int*)lB1, 16, 0, 0);
        gA0 += 32; gA1 += 32; gB0 += 32; gB1 += 32;
        asm volatile("s_waitcnt vmcnt(0)" ::: "memory");
        __syncthreads();

        short8 af[4], bf[4];
#pragma unroll
        for (int i = 0; i < 4; ++i) af[i] = *(const short8*)(lds + aoff[i]);
#pragma unroll
        for (int j = 0; j < 4; ++j) bf[j] = *(const short8*)(lds + boff[j]);
#pragma unroll
        for (int i = 0; i < 4; ++i)
#pragma unroll
            for (int j = 0; j < 4; ++j)
                acc[i][j] = __builtin_amdgcn_mfma_f32_16x16x32_bf16(af[i], bf[j], acc[i][j], 0, 0, 0);
    }

    if (QKV_EPI) {
#pragma unroll
        for (int j = 0; j < 4; ++j) {
            int col = bn*128 + wn*64 + j*16 + r;     // [0,2304)
            int t = col / CC;
            int rem = col - t*CC;
            int h = rem >> 6, d = rem & 63;
            if (t == 2) {
#pragma unroll
                for (int i = 0; i < 4; ++i) {
                    int m0 = bm*128 + wm*64 + i*16 + quad*4;
                    int b = m0 >> 9, n0 = m0 & 511;
                    float4 o4 = {acc[i][j][0], acc[i][j][1], acc[i][j][2], acc[i][j][3]};
                    *(float4*)(vt + ((size_t)((b*HH + h)*HD + d))*NN + n0) = o4;
                }
            } else {
                unsigned short* ph = (t == 0) ? qh : kh;
                unsigned short* pl = (t == 0) ? ql : kl;
#pragma unroll
                for (int i = 0; i < 4; ++i) {
#pragma unroll
                    for (int e = 0; e < 4; ++e) {
                        int m = bm*128 + wm*64 + i*16 + quad*4 + e;
                        int b = m >> 9, nrow = m & 511;
                        size_t idx = ((size_t)(b*HH + h)*NN + nrow)*HD + d;
                        float val = acc[i][j][e];
                        unsigned short hi = f2bf(val);
                        ph[idx] = hi;
                        pl[idx] = f2bf(val - bf2f(hi));
                    }
                }
            }
        }
    } else {
#pragma unroll
        for (int j = 0; j < 4; ++j) {
            int col = bn*128 + wn*64 + j*16 + r;
            float bv = bias[col];
#pragma unroll
            for (int i = 0; i < 4; ++i) {
#pragma unroll
                for (int e = 0; e < 4; ++e) {
                    int m = bm*128 + wm*64 + i*16 + quad*4 + e;
                    out[(size_t)m*NCOLS + col] = acc[i][j][e] + bv;
                }
            }
        }
    }
}

// ---------------------------------------------------------------------------
// MFMA scores + exact top-k + softmax.
// launch_bounds(256,1): 512-reg/wave budget -> no spill of acc[32]+key[32].
// Select: keys lifted from acc ONCE into key[32] (VGPR); bit-serial radix
// starting at the first differing bit (per-quarter OR/AND), per-quad bit
// counters, early exit.  XCD swizzle: bh = blk%96 so a head's 8 row-blocks
// share id%8 -> same XCD L2 for K.
// ---------------------------------------------------------------------------
__global__ __launch_bounds__(256, 1) void attn_scores_k(
        const unsigned short* __restrict__ qh, const unsigned short* __restrict__ ql,
        const unsigned short* __restrict__ kh, const unsigned short* __restrict__ kl,
        const int* __restrict__ islast, float* __restrict__ attn) {

    __shared__ unsigned short qs[2][64][72];
    __shared__ char ks[16384];

    const int bh = blockIdx.x % 96;
    const int rb = blockIdx.x / 96;
    const int tid = threadIdx.x;
    const int wv = tid >> 6, lane = tid & 63;
    const int quad = lane >> 4, r = lane & 15;

    const unsigned short* gq[2] = { qh + ((size_t)bh*NN + rb*64)*HD,
                                    ql + ((size_t)bh*NN + rb*64)*HD };
#pragma unroll
    for (int i = 0; i < 4; ++i) {
        int s = tid + i*256;
        int hl = s >> 9, s2 = s & 511;
        int row = s2 >> 3, oct = s2 & 7;
        short8 val = *(const short8*)(gq[hl] + row*HD + oct*8);
        *(short8*)&qs[hl][row][oct*8] = val;
    }
    __syncthreads();

    short8 afr[6];
    {
        const int arow = wv*16 + r;
#pragma unroll
        for (int t = 0; t < 3; ++t) {
            int src = (t == 2) ? 1 : 0;
#pragma unroll
            for (int half = 0; half < 2; ++half)
                afr[t*2+half] = *(const short8*)&qs[src][arow][half*32 + quad*8];
        }
    }

    floatx4 acc[32];
#pragma unroll
    for (int ct = 0; ct < 32; ++ct) acc[ct] = (floatx4){0.f,0.f,0.f,0.f};

    const unsigned short* gk[2] = { kh + (size_t)bh*NN*HD, kl + (size_t)bh*NN*HD };

    for (int ch = 0; ch < 8; ++ch) {
        __syncthreads();
#pragma unroll
        for (int i = 0; i < 4; ++i) {
            int s = tid + i*256;
            int hl = s >> 9, s2 = s & 511;
            int row = s2 >> 3, octp = s2 & 7;
            int oct = octp ^ (row & 7);
            const unsigned short* src = gk[hl] + (size_t)(ch*64 + row)*HD + oct*8;
            __builtin_amdgcn_global_load_lds(
                (const __attribute__((address_space(1))) unsigned int*)src,
                (__attribute__((address_space(3))) unsigned int*)(ks + (size_t)(i*256 + wv*64)*16),
                16, 0, 0);
        }
        asm volatile("s_waitcnt vmcnt(0)" ::: "memory");
        __syncthreads();

#pragma unroll
        for (int ctl = 0; ctl < 4; ++ctl) {
            const int ct = ch*4 + ctl;
            const int n = ctl*16 + r;
#pragma unroll
            for (int t = 0; t < 3; ++t) {
                const int srcB = (t == 1) ? 1 : 0;
#pragma unroll
                for (int half = 0; half < 2; ++half) {
                    const int oct = (half*4 + quad) ^ (n & 7);
                    short8 bfr = *(const short8*)(ks + srcB*8192 + n*128 + oct*16);
                    acc[ct] = __builtin_amdgcn_mfma_f32_16x16x32_bf16(afr[t*2+half], bfr, acc[ct], 0, 0, 0);
                }
            }
        }
    }

    const int lastv = islast[0];

#pragma unroll
    for (int e = 0; e < 4; ++e) {
        // lift this row's 32 scaled keys out of acc ONCE (ordered-uint)
        unsigned int key[32];
#pragma unroll
        for (int ct = 0; ct < 32; ++ct) {
            unsigned int t = __float_as_uint(acc[ct][e] * 0.125f);
            key[ct] = (t & 0x80000000u) ? ~t : (t | 0x80000000u);
        }

        unsigned int kth = 0u;
        if (!lastv) {
            unsigned int uo = key[0], ua = key[0];
#pragma unroll
            for (int ct = 1; ct < 32; ++ct) { uo |= key[ct]; ua &= key[ct]; }
#pragma unroll
            for (int off = 1; off <= 8; off <<= 1) {
                uo |= __shfl_xor(uo, off);
                ua &= __shfl_xor(ua, off);
            }
            unsigned int diff = uo ^ ua;
            int bit = 31 - __clz(diff);            // -1 if all keys equal
            unsigned int am = 0xFFFFFFFFu;
            int kk = TOPK, cntA = 512;
            int done = (diff == 0u);
            while (__ballot(!done) != 0ull) {
                if (!done) {
                    unsigned int m1 = 0u;
#pragma unroll
                    for (int ct = 0; ct < 32; ++ct)
                        m1 |= ((key[ct] >> bit) & 1u) << ct;
                    int c1 = __popc(am & m1);
                    c1 += __shfl_xor(c1, 1);
                    c1 += __shfl_xor(c1, 2);
                    c1 += __shfl_xor(c1, 4);
                    c1 += __shfl_xor(c1, 8);
                    if (kk <= c1) { am &= m1; cntA = c1; }
                    else          { kk -= c1; am &= ~m1; cntA -= c1; }
                    --bit;
                    done = (cntA == kk) | (kk == 1) | (bit < 0);
                }
            }
            unsigned int mn = 0xFFFFFFFFu, mx = 0u;
#pragma unroll
            for (int ct = 0; ct < 32; ++ct) {
                if ((am >> ct) & 1u) {
                    mn = mn < key[ct] ? mn : key[ct];
                    mx = mx > key[ct] ? mx : key[ct];
                }
            }
#pragma unroll
            for (int off = 1; off <= 8; off <<= 1) {
                unsigned int mns = __shfl_xor(mn, off), mxs = __shfl_xor(mx, off);
                mn = mn < mns ? mn : mns; mx = mx > mxs ? mx : mxs;
            }
            kth = (kk == 1) ? mx : mn;
        }

        // masked softmax from key[] (VGPR-resident)
        unsigned int umx = key[0];
#pragma unroll
        for (int ct = 1; ct < 32; ++ct) umx = umx > key[ct] ? umx : key[ct];
#pragma unroll
        for (int off = 1; off <= 8; off <<= 1) {
            unsigned int t2 = __shfl_xor(umx, off);
            umx = umx > t2 ? umx : t2;
        }
        float fmx = __uint_as_float((umx & 0x80000000u) ? (umx & 0x7FFFFFFFu) : ~umx);
        float sum = 0.f;
#pragma unroll
        for (int ct = 0; ct < 32; ++ct) {
            unsigned int uu = key[ct];
            float f = __uint_as_float((uu & 0x80000000u) ? (uu & 0x7FFFFFFFu) : ~uu);
            float ev = (lastv || uu >= kth) ? __expf(f - fmx) : 0.f;
            acc[ct][e] = ev;
            sum += ev;
        }
#pragma unroll
        for (int off = 1; off <= 8; off <<= 1) sum += __shfl_xor(sum, off);
        const float inv = 1.f / sum;
        float* arow = attn + ((size_t)bh*NN + rb*64 + wv*16 + quad*4 + e) * NN;
#pragma unroll
        for (int ct = 0; ct < 32; ++ct) arow[ct*16 + r] = acc[ct][e] * inv;
    }
}

// ---------------------------------------------------------------------------
// MFMA PV:  O[64 x 64] = P[64 x 512] @ V[512 x 64] per (head, row-tile).
// P bf16; V = vh + vl from transposed fp32 vt.  Epilogue: split-bf16 o.
// ---------------------------------------------------------------------------
__global__ __launch_bounds__(256) void attn_pv_k(const float* __restrict__ attn,
                                                 const float* __restrict__ vt,
                                                 unsigned short* __restrict__ Ao) {
    __shared__ unsigned short pls[64][72];
    __shared__ unsigned short vhs[64][72];
    __shared__ unsigned short vls[64][72];

    const int blk = blockIdx.x;
    const int bh  = blk % 96;
    const int rb  = blk / 96;
    const int b = bh / HH, h = bh % HH;
    const int tid = threadIdx.x;
    const int wv = tid >> 6, lane = tid & 63;
    const int quad = lane >> 4, r = lane & 15;

    const int sm = tid >> 2;           // staging row 0..63
    const int sk = (tid & 3) * 16;     // staging col base
    const float* prow = attn + ((size_t)bh*NN + rb*64 + sm) * NN + sk;
    const float* vrow = vt + ((size_t)bh*HD + sm) * NN + sk;

    floatx4 accO[4];
#pragma unroll
    for (int j = 0; j < 4; ++j) accO[j] = (floatx4){0.f,0.f,0.f,0.f};

    for (int ch = 0; ch < 8; ++ch) {
        float pv[16], vv[16];
#pragma unroll
        for (int x = 0; x < 4; ++x) {
            *(float4*)&pv[x*4] = *(const float4*)(prow + ch*64 + x*4);
            *(float4*)&vv[x*4] = *(const float4*)(vrow + ch*64 + x*4);
        }
        __syncthreads();
        unsigned short tp[16], th[16], tl[16];
#pragma unroll
        for (int x = 0; x < 16; ++x) {
            tp[x] = f2bf(pv[x]);
            th[x] = f2bf(vv[x]);
            tl[x] = f2bf(vv[x] - bf2f(th[x]));
        }
        *(short8*)&pls[sm][sk]   = *(short8*)&tp[0];
        *(short8*)&pls[sm][sk+8] = *(short8*)&tp[8];
        *(short8*)&vhs[sm][sk]   = *(short8*)&th[0];
        *(short8*)&vhs[sm][sk+8] = *(short8*)&th[8];
        *(short8*)&vls[sm][sk]   = *(short8*)&tl[0];
        *(short8*)&vls[sm][sk+8] = *(short8*)&tl[8];
        __syncthreads();

#pragma unroll
        for (int kb = 0; kb < 2; ++kb) {
            short8 af = *(const short8*)&pls[wv*16 + r][kb*32 + quad*8];
#pragma unroll
            for (int j = 0; j < 4; ++j) {
                short8 bh8 = *(const short8*)&vhs[j*16 + r][kb*32 + quad*8];
                short8 bl8 = *(const short8*)&vls[j*16 + r][kb*32 + quad*8];
                accO[j] = __builtin_amdgcn_mfma_f32_16x16x32_bf16(af, bh8, accO[j], 0, 0, 0);
                accO[j] = __builtin_amdgcn_mfma_f32_16x16x32_bf16(af, bl8, accO[j], 0, 0, 0);
            }
        }
    }

#pragma unroll
    for (int j = 0; j < 4; ++j) {
        int d = j*16 + r;
#pragma unroll
        for (int e = 0; e < 4; ++e) {
            int n = rb*64 + wv*16 + quad*4 + e;
            size_t mrow = (size_t)b*NN + n;
            float val = accO[j][e];
            unsigned short hi = f2bf(val);
            unsigned short lo = f2bf(val - bf2f(hi));
            unsigned short* base = Ao + mrow*KC + h*HD + d;
            base[0] = hi; base[CC] = hi; base[2*CC] = lo;
        }
    }
}

// ---------------------------------------------------------------------------
extern "C" void kernel_launch(void* const* d_in, const int* in_sizes, int n_in,
                              void* d_out, int out_size, void* d_ws, size_t ws_size,
                              hipStream_t stream) {
    const float* x      = (const float*)d_in[0];
    const float* qkv_w  = (const float*)d_in[1];
    const float* proj_w = (const float*)d_in[2];
    const float* proj_b = (const float*)d_in[3];
    const int*   islast = (const int*)d_in[4];

    float* out  = (float*)d_out;                       // [B,N,C]
    float* attn = out + (size_t)BB*NN*CC;              // [B,H,N,N]

    float* ws = (float*)d_ws;
    float* vt = ws;                                    // [B,H,hd,N] fp32 (transposed v)
    unsigned short* qhp = (unsigned short*)(ws + (size_t)QKV_ELEMS);
    unsigned short* qlp = qhp + (size_t)QKV_ELEMS;
    unsigned short* khp = qlp + (size_t)QKV_ELEMS;
    unsigned short* klp = khp + (size_t)QKV_ELEMS;
    unsigned short* Asp   = klp + (size_t)QKV_ELEMS;   // [4096][2304]
    unsigned short* Bqkv  = Asp  + (size_t)4096*KC;    // [2304][2304]
    unsigned short* Bproj = Bqkv + (size_t)2304*KC;    // [768][2304]

    split_k<true> <<<dim3(4096*CC/4/256), 256, 0, stream>>>(x,      Asp,   4096*CC/4);
    split_k<false><<<dim3(2304*CC/4/256), 256, 0, stream>>>(qkv_w,  Bqkv,  2304*CC/4);
    split_k<false><<<dim3(CC*CC/4/256),   256, 0, stream>>>(proj_w, Bproj, CC*CC/4);

    gemm_split<0, true>  <<<dim3(32, 18), 256, 0, stream>>>(Asp, Bqkv, nullptr, nullptr,
                                                            qhp, qlp, khp, klp, vt);
    attn_scores_k        <<<dim3(96*8),   256, 0, stream>>>(qhp, qlp, khp, klp, islast, attn);
    attn_pv_k            <<<dim3(96*8),   256, 0, stream>>>(attn, vt, Asp);
    gemm_split<CC, false><<<dim3(32, 6),  256, 0, stream>>>(Asp, Bproj, proj_b, out,
                                                            nullptr, nullptr, nullptr, nullptr, nullptr);
}

// Round 7
// 356.273 us; speedup vs baseline: 1.3185x; 1.0279x over previous
//
#include <hip/hip_runtime.h>
#include <math.h>

#define BB 8
#define NN 512
#define CC 768
#define HH 12
#define HD 64
#define TOPK 90
#define QKV_ELEMS (BB*HH*NN*HD)   // 3145728 elements per q/k/v tensor
#define KC 2304                   // split-K: 3*768

typedef __attribute__((ext_vector_type(8))) short short8;   // 8 bf16 = 4 VGPR
typedef __attribute__((ext_vector_type(4))) float floatx4;  // MFMA C/D

__device__ inline unsigned short f2bf(float f) {
    unsigned int u = __float_as_uint(f);
    u += 0x7FFFu + ((u >> 16) & 1u);           // RNE
    return (unsigned short)(u >> 16);
}
__device__ inline float bf2f(unsigned short h) {
    return __uint_as_float(((unsigned int)h) << 16);
}

// ---------------------------------------------------------------------------
// Split kernels: fp32 [rows][768] -> bf16 [rows][2304].
// IS_A: blocks [hi | hi | lo]; !IS_A: blocks [hi | lo | hi]  (hh+hl+lh).
// ---------------------------------------------------------------------------
template<bool IS_A>
__global__ __launch_bounds__(256) void split_k(const float* __restrict__ in,
                                               unsigned short* __restrict__ o2,
                                               int total) {
    int idx = blockIdx.x * 256 + threadIdx.x;
    if (idx >= total) return;
    int e = idx * 4;
    int m = e / CC, kk = e - m * CC;
    float4 f = *(const float4*)(in + e);
    ushort4 hi, lo;
    hi.x = f2bf(f.x); lo.x = f2bf(f.x - bf2f(hi.x));
    hi.y = f2bf(f.y); lo.y = f2bf(f.y - bf2f(hi.y));
    hi.z = f2bf(f.z); lo.z = f2bf(f.z - bf2f(hi.z));
    hi.w = f2bf(f.w); lo.w = f2bf(f.w - bf2f(hi.w));
    unsigned short* base = o2 + (size_t)m * KC + kk;
    *(ushort4*)(base)        = hi;
    *(ushort4*)(base + CC)   = IS_A ? hi : lo;
    *(ushort4*)(base + 2*CC) = IS_A ? lo : hi;
}

// ---------------------------------------------------------------------------
// Split-bf16 MFMA GEMM, BK=64 (32 MFMA per barrier-pair, 36 iters).
// QKV_EPI: q,k -> split bf16 planes [B,H,N,hd]; v -> split bf16 TRANSPOSED
// planes vth/vtl [B,H,hd,N].  Else: out[m][NCOLS] + bias.
// ---------------------------------------------------------------------------
template<int NCOLS, bool QKV_EPI>
__global__ __launch_bounds__(256) void gemm_split(const unsigned short* __restrict__ A,
                                                  const unsigned short* __restrict__ Bm,
                                                  const float* __restrict__ bias,
                                                  float* __restrict__ out,
                                                  unsigned short* __restrict__ qh,
                                                  unsigned short* __restrict__ ql,
                                                  unsigned short* __restrict__ kh,
                                                  unsigned short* __restrict__ kl,
                                                  unsigned short* __restrict__ vth,
                                                  unsigned short* __restrict__ vtl) {
    __shared__ char lds[32768];          // A tile 16KB @0, B tile 16KB @16384
    const int bm = blockIdx.x, bn = blockIdx.y;
    const int tid  = threadIdx.x;
    const int wave = tid >> 6, lane = tid & 63;
    const int wm = wave >> 1, wn = wave & 1;
    const int quad = lane >> 4, r = lane & 15;

    // staging pointers: inst i, chunk c = tid + i*256 (c in [0,2048));
    // matrix = c>>10; s = c&1023; m = s>>3; octp = s&7; oct = octp ^ (m&7)
    const unsigned short* gbase[8];
#pragma unroll
    for (int i = 0; i < 8; ++i) {
        int c = tid + i*256;
        int s = c & 1023;
        int m = s >> 3, octp = s & 7, oct = octp ^ (m & 7);
        gbase[i] = (i < 4 ? A  + (size_t)(bm*128 + m) * KC
                          : Bm + (size_t)(bn*128 + m) * KC) + oct*8;
    }

    // fragment LDS offsets: row stored as 8 octets of 16B, oct = kslot ^ (row&7)
    int aoff[2][4], boff[2][4];
#pragma unroll
    for (int kb = 0; kb < 2; ++kb)
#pragma unroll
        for (int i = 0; i < 4; ++i) {
            int ra = wm*64 + i*16 + r;
            int rb2 = wn*64 + i*16 + r;
            aoff[kb][i] = (ra*8 + ((kb*4 + quad) ^ (ra & 7))) * 16;
            boff[kb][i] = 16384 + (rb2*8 + ((kb*4 + quad) ^ (rb2 & 7))) * 16;
        }

    floatx4 acc[4][4];
#pragma unroll
    for (int i = 0; i < 4; ++i)
#pragma unroll
        for (int j = 0; j < 4; ++j)
            acc[i][j] = (floatx4){0.f, 0.f, 0.f, 0.f};

    for (int it = 0; it < KC/64; ++it) {
        __syncthreads();
#pragma unroll
        for (int i = 0; i < 8; ++i) {
            __builtin_amdgcn_global_load_lds(
                (const __attribute__((address_space(1))) unsigned int*)gbase[i],
                (__attribute__((address_space(3))) unsigned int*)(lds + i*4096 + wave*1024),
                16, 0, 0);
            gbase[i] += 64;
        }
        asm volatile("s_waitcnt vmcnt(0)" ::: "memory");
        __syncthreads();

#pragma unroll
        for (int kb = 0; kb < 2; ++kb) {
            short8 af[4], bf[4];
#pragma unroll
            for (int i = 0; i < 4; ++i) af[i] = *(const short8*)(lds + aoff[kb][i]);
#pragma unroll
            for (int j = 0; j < 4; ++j) bf[j] = *(const short8*)(lds + boff[kb][j]);
#pragma unroll
            for (int i = 0; i < 4; ++i)
#pragma unroll
                for (int j = 0; j < 4; ++j)
                    acc[i][j] = __builtin_amdgcn_mfma_f32_16x16x32_bf16(af[i], bf[j], acc[i][j], 0, 0, 0);
        }
    }

    if (QKV_EPI) {
#pragma unroll
        for (int j = 0; j < 4; ++j) {
            int col = bn*128 + wn*64 + j*16 + r;     // [0,2304)
            int t = col / CC;
            int rem = col - t*CC;
            int h = rem >> 6, d = rem & 63;
            if (t == 2) {
                // v transposed split: vth/vtl[(bh*64+d)*512 + n], ushort4 over 4 rows
#pragma unroll
                for (int i = 0; i < 4; ++i) {
                    int m0 = bm*128 + wm*64 + i*16 + quad*4;
                    int b = m0 >> 9, n0 = m0 & 511;
                    ushort4 hi, lo;
                    hi.x = f2bf(acc[i][j][0]); lo.x = f2bf(acc[i][j][0] - bf2f(hi.x));
                    hi.y = f2bf(acc[i][j][1]); lo.y = f2bf(acc[i][j][1] - bf2f(hi.y));
                    hi.z = f2bf(acc[i][j][2]); lo.z = f2bf(acc[i][j][2] - bf2f(hi.z));
                    hi.w = f2bf(acc[i][j][3]); lo.w = f2bf(acc[i][j][3] - bf2f(hi.w));
                    size_t off = ((size_t)((b*HH + h)*HD + d))*NN + n0;
                    *(ushort4*)(vth + off) = hi;
                    *(ushort4*)(vtl + off) = lo;
                }
            } else {
                unsigned short* ph = (t == 0) ? qh : kh;
                unsigned short* pl = (t == 0) ? ql : kl;
#pragma unroll
                for (int i = 0; i < 4; ++i) {
#pragma unroll
                    for (int e = 0; e < 4; ++e) {
                        int m = bm*128 + wm*64 + i*16 + quad*4 + e;
                        int b = m >> 9, nrow = m & 511;
                        size_t idx = ((size_t)(b*HH + h)*NN + nrow)*HD + d;
                        float val = acc[i][j][e];
                        unsigned short hi = f2bf(val);
                        ph[idx] = hi;
                        pl[idx] = f2bf(val - bf2f(hi));
                    }
                }
            }
        }
    } else {
#pragma unroll
        for (int j = 0; j < 4; ++j) {
            int col = bn*128 + wn*64 + j*16 + r;
            float bv = bias[col];
#pragma unroll
            for (int i = 0; i < 4; ++i) {
#pragma unroll
                for (int e = 0; e < 4; ++e) {
                    int m = bm*128 + wm*64 + i*16 + quad*4 + e;
                    out[(size_t)m*NCOLS + col] = acc[i][j][e] + bv;
                }
            }
        }
    }
}

// ---------------------------------------------------------------------------
// FUSED: MFMA scores + exact top-k + softmax + PV.
// Phases 0-2 as round 6 (verified).  Phase 3: P (already in acc regs,
// C-layout) is round-tripped per 64-col chunk through LDS into A-operand
// layout; V^T chunks (pre-split bf16 planes vth/vtl) staged via
// global_load_lds; O accumulated with MFMA; epilogue writes split-bf16 o
// [hi|hi|lo] into Ao for the proj GEMM.  attn_pv_k is gone.
// ---------------------------------------------------------------------------
__global__ __launch_bounds__(256, 1) void attn_scores_k(
        const unsigned short* __restrict__ qh, const unsigned short* __restrict__ ql,
        const unsigned short* __restrict__ kh, const unsigned short* __restrict__ kl,
        const unsigned short* __restrict__ vth, const unsigned short* __restrict__ vtl,
        const int* __restrict__ islast, float* __restrict__ attn,
        unsigned short* __restrict__ Ao) {

    __shared__ char smem[34816];
    // phase 0/1: qs = ushort[2][64][72] @0 (18432 B); ks @18432 (16384 B)
    // phase 3:   pls = ushort[64][80] @0 (10240 B); vhs @10240; vls @18432 (8192 each)
    unsigned short* qs = (unsigned short*)smem;
    char* ks = smem + 18432;

    const int bh = blockIdx.x % 96;
    const int rb = blockIdx.x / 96;
    const int tid = threadIdx.x;
    const int wv = tid >> 6, lane = tid & 63;
    const int quad = lane >> 4, r = lane & 15;
    const int b = bh / HH, h = bh % HH;

    const unsigned short* gq[2] = { qh + ((size_t)bh*NN + rb*64)*HD,
                                    ql + ((size_t)bh*NN + rb*64)*HD };
#pragma unroll
    for (int i = 0; i < 4; ++i) {
        int s = tid + i*256;
        int hl = s >> 9, s2 = s & 511;
        int row = s2 >> 3, oct = s2 & 7;
        short8 val = *(const short8*)(gq[hl] + row*HD + oct*8);
        *(short8*)&qs[(hl*64 + row)*72 + oct*8] = val;
    }
    __syncthreads();

    short8 afr[6];
    {
        const int arow = wv*16 + r;
#pragma unroll
        for (int t = 0; t < 3; ++t) {
            int src = (t == 2) ? 1 : 0;
#pragma unroll
            for (int half = 0; half < 2; ++half)
                afr[t*2+half] = *(const short8*)&qs[(src*64 + arow)*72 + half*32 + quad*8];
        }
    }

    floatx4 acc[32];
#pragma unroll
    for (int ct = 0; ct < 32; ++ct) acc[ct] = (floatx4){0.f,0.f,0.f,0.f};

    const unsigned short* gk[2] = { kh + (size_t)bh*NN*HD, kl + (size_t)bh*NN*HD };

    for (int ch = 0; ch < 8; ++ch) {
        __syncthreads();
#pragma unroll
        for (int i = 0; i < 4; ++i) {
            int s = tid + i*256;
            int hl = s >> 9, s2 = s & 511;
            int row = s2 >> 3, octp = s2 & 7;
            int oct = octp ^ (row & 7);
            const unsigned short* src = gk[hl] + (size_t)(ch*64 + row)*HD + oct*8;
            __builtin_amdgcn_global_load_lds(
                (const __attribute__((address_space(1))) unsigned int*)src,
                (__attribute__((address_space(3))) unsigned int*)(ks + (size_t)(i*256 + wv*64)*16),
                16, 0, 0);
        }
        asm volatile("s_waitcnt vmcnt(0)" ::: "memory");
        __syncthreads();

#pragma unroll
        for (int ctl = 0; ctl < 4; ++ctl) {
            const int ct = ch*4 + ctl;
            const int n = ctl*16 + r;
#pragma unroll
            for (int t = 0; t < 3; ++t) {
                const int srcB = (t == 1) ? 1 : 0;
#pragma unroll
                for (int half = 0; half < 2; ++half) {
                    const int oct = (half*4 + quad) ^ (n & 7);
                    short8 bfr = *(const short8*)(ks + srcB*8192 + n*128 + oct*16);
                    acc[ct] = __builtin_amdgcn_mfma_f32_16x16x32_bf16(afr[t*2+half], bfr, acc[ct], 0, 0, 0);
                }
            }
        }
    }

    const int lastv = islast[0];

    // ---- phase 2: per reg-row e: exact top-k (register radix) + softmax ----
#pragma unroll
    for (int e = 0; e < 4; ++e) {
        unsigned int key[32];
#pragma unroll
        for (int ct = 0; ct < 32; ++ct) {
            unsigned int t = __float_as_uint(acc[ct][e] * 0.125f);
            key[ct] = (t & 0x80000000u) ? ~t : (t | 0x80000000u);
        }

        unsigned int kth = 0u;
        if (!lastv) {
            unsigned int uo = key[0], ua = key[0];
#pragma unroll
            for (int ct = 1; ct < 32; ++ct) { uo |= key[ct]; ua &= key[ct]; }
#pragma unroll
            for (int off = 1; off <= 8; off <<= 1) {
                uo |= __shfl_xor(uo, off);
                ua &= __shfl_xor(ua, off);
            }
            unsigned int diff = uo ^ ua;
            int bit = 31 - __clz(diff);
            unsigned int am = 0xFFFFFFFFu;
            int kk = TOPK, cntA = 512;
            int done = (diff == 0u);
            while (__ballot(!done) != 0ull) {
                if (!done) {
                    unsigned int m1 = 0u;
#pragma unroll
                    for (int ct = 0; ct < 32; ++ct)
                        m1 |= ((key[ct] >> bit) & 1u) << ct;
                    int c1 = __popc(am & m1);
                    c1 += __shfl_xor(c1, 1);
                    c1 += __shfl_xor(c1, 2);
                    c1 += __shfl_xor(c1, 4);
                    c1 += __shfl_xor(c1, 8);
                    if (kk <= c1) { am &= m1; cntA = c1; }
                    else          { kk -= c1; am &= ~m1; cntA -= c1; }
                    --bit;
                    done = (cntA == kk) | (kk == 1) | (bit < 0);
                }
            }
            unsigned int mn = 0xFFFFFFFFu, mx = 0u;
#pragma unroll
            for (int ct = 0; ct < 32; ++ct) {
                if ((am >> ct) & 1u) {
                    mn = mn < key[ct] ? mn : key[ct];
                    mx = mx > key[ct] ? mx : key[ct];
                }
            }
#pragma unroll
            for (int off = 1; off <= 8; off <<= 1) {
                unsigned int mns = __shfl_xor(mn, off), mxs = __shfl_xor(mx, off);
                mn = mn < mns ? mn : mns; mx = mx > mxs ? mx : mxs;
            }
            kth = (kk == 1) ? mx : mn;
        }

        unsigned int umx = key[0];
#pragma unroll
        for (int ct = 1; ct < 32; ++ct) umx = umx > key[ct] ? umx : key[ct];
#pragma unroll
        for (int off = 1; off <= 8; off <<= 1) {
            unsigned int t2 = __shfl_xor(umx, off);
            umx = umx > t2 ? umx : t2;
        }
        float fmx = __uint_as_float((umx & 0x80000000u) ? (umx & 0x7FFFFFFFu) : ~umx);
        float sum = 0.f;
#pragma unroll
        for (int ct = 0; ct < 32; ++ct) {
            unsigned int uu = key[ct];
            float f = __uint_as_float((uu & 0x80000000u) ? (uu & 0x7FFFFFFFu) : ~uu);
            float ev = (lastv || uu >= kth) ? __expf(f - fmx) : 0.f;
            acc[ct][e] = ev;
            sum += ev;
        }
#pragma unroll
        for (int off = 1; off <= 8; off <<= 1) sum += __shfl_xor(sum, off);
        const float inv = 1.f / sum;
        float* arow = attn + ((size_t)bh*NN + rb*64 + wv*16 + quad*4 + e) * NN;
#pragma unroll
        for (int ct = 0; ct < 32; ++ct) {
            float p = acc[ct][e] * inv;
            acc[ct][e] = p;                  // keep normalized P in regs for PV
            arow[ct*16 + r] = p;
        }
    }

    // ---- phase 3: O = P @ V  (P in acc regs; 8 chunks of 64 K-cols) ----
    unsigned short* pls = (unsigned short*)smem;   // [64][80]
    char* vhs = smem + 10240;
    char* vls = smem + 18432;
    const unsigned short* gvh = vth + (size_t)bh*HD*NN;
    const unsigned short* gvl = vtl + (size_t)bh*HD*NN;

    floatx4 accO[4];
#pragma unroll
    for (int j = 0; j < 4; ++j) accO[j] = (floatx4){0.f,0.f,0.f,0.f};

    for (int ch = 0; ch < 8; ++ch) {
        __syncthreads();   // prev chunk reads done (first iter: phases 0-2 done)
        // write this wave's 16x64 P chunk as bf16 (C-layout -> [row][col])
#pragma unroll
        for (int ctl = 0; ctl < 4; ++ctl) {
            int col = ctl*16 + r;
#pragma unroll
            for (int e = 0; e < 4; ++e)
                pls[(wv*16 + quad*4 + e)*80 + col] = f2bf(acc[ch*4 + ctl][e]);
        }
        // stage V^T chunk (rows d=0..63, cols m=ch*64..+63), hi+lo planes
#pragma unroll
        for (int i = 0; i < 2; ++i) {
            int s = tid + i*256;
            int d = s >> 3, octp = s & 7, oct = octp ^ (d & 7);
            size_t goff = (size_t)d*NN + ch*64 + oct*8;
            __builtin_amdgcn_global_load_lds(
                (const __attribute__((address_space(1))) unsigned int*)(gvh + goff),
                (__attribute__((address_space(3))) unsigned int*)(vhs + (i*256 + wv*64)*16),
                16, 0, 0);
            __builtin_amdgcn_global_load_lds(
                (const __attribute__((address_space(1))) unsigned int*)(gvl + goff),
                (__attribute__((address_space(3))) unsigned int*)(vls + (i*256 + wv*64)*16),
                16, 0, 0);
        }
        asm volatile("s_waitcnt vmcnt(0)" ::: "memory");
        __syncthreads();

#pragma unroll
        for (int kb = 0; kb < 2; ++kb) {
            short8 af = *(const short8*)&pls[(wv*16 + r)*80 + kb*32 + quad*8];
#pragma unroll
            for (int j = 0; j < 4; ++j) {
                int d = j*16 + r;
                int oct = (kb*4 + quad) ^ (d & 7);
                short8 bh8 = *(const short8*)(vhs + d*128 + oct*16);
                short8 bl8 = *(const short8*)(vls + d*128 + oct*16);
                accO[j] = __builtin_amdgcn_mfma_f32_16x16x32_bf16(af, bh8, accO[j], 0, 0, 0);
                accO[j] = __builtin_amdgcn_mfma_f32_16x16x32_bf16(af, bl8, accO[j], 0, 0, 0);
            }
        }
    }

    // ---- epilogue: split-bf16 o [hi|hi|lo] into Ao ----
#pragma unroll
    for (int j = 0; j < 4; ++j) {
        int d = j*16 + r;
#pragma unroll
        for (int e = 0; e < 4; ++e) {
            int n = rb*64 + wv*16 + quad*4 + e;
            size_t mrow = (size_t)b*NN + n;
            float val = accO[j][e];
            unsigned short hi = f2bf(val);
            unsigned short lo = f2bf(val - bf2f(hi));
            unsigned short* base = Ao + mrow*KC + h*HD + d;
            base[0] = hi; base[CC] = hi; base[2*CC] = lo;
        }
    }
}

// ---------------------------------------------------------------------------
extern "C" void kernel_launch(void* const* d_in, const int* in_sizes, int n_in,
                              void* d_out, int out_size, void* d_ws, size_t ws_size,
                              hipStream_t stream) {
    const float* x      = (const float*)d_in[0];
    const float* qkv_w  = (const float*)d_in[1];
    const float* proj_w = (const float*)d_in[2];
    const float* proj_b = (const float*)d_in[3];
    const int*   islast = (const int*)d_in[4];

    float* out  = (float*)d_out;                       // [B,N,C]
    float* attn = out + (size_t)BB*NN*CC;              // [B,H,N,N]

    unsigned short* us = (unsigned short*)d_ws;
    unsigned short* vth = us;                          // [B,H,hd,N] bf16 hi
    unsigned short* vtl = vth + (size_t)QKV_ELEMS;     // [B,H,hd,N] bf16 lo
    unsigned short* qhp = vtl + (size_t)QKV_ELEMS;
    unsigned short* qlp = qhp + (size_t)QKV_ELEMS;
    unsigned short* khp = qlp + (size_t)QKV_ELEMS;
    unsigned short* klp = khp + (size_t)QKV_ELEMS;
    unsigned short* Asp   = klp + (size_t)QKV_ELEMS;   // [4096][2304]
    unsigned short* Bqkv  = Asp  + (size_t)4096*KC;    // [2304][2304]
    unsigned short* Bproj = Bqkv + (size_t)2304*KC;    // [768][2304]

    split_k<true> <<<dim3(4096*CC/4/256), 256, 0, stream>>>(x,      Asp,   4096*CC/4);
    split_k<false><<<dim3(2304*CC/4/256), 256, 0, stream>>>(qkv_w,  Bqkv,  2304*CC/4);
    split_k<false><<<dim3(CC*CC/4/256),   256, 0, stream>>>(proj_w, Bproj, CC*CC/4);

    gemm_split<0, true>  <<<dim3(32, 18), 256, 0, stream>>>(Asp, Bqkv, nullptr, nullptr,
                                                            qhp, qlp, khp, klp, vth, vtl);
    attn_scores_k        <<<dim3(96*8),   256, 0, stream>>>(qhp, qlp, khp, klp, vth, vtl,
                                                            islast, attn, Asp);
    gemm_split<CC, false><<<dim3(32, 6),  256, 0, stream>>>(Asp, Bproj, proj_b, out,
                                                            nullptr, nullptr, nullptr, nullptr,
                                                            nullptr, nullptr);
}